// Round 7
// baseline (246.746 us; speedup 1.0000x reference)
//
#include <hip/hip_runtime.h>
#include <hip/hip_cooperative_groups.h>
#include <math.h>

namespace cg = cooperative_groups;

constexpr int CL = 256;
constexpr int CD = 768;
constexpr int CATT = 100;
constexpr int CH = 5;
constexpr int CDK = 20;

__device__ __forceinline__ void fma4(float4& a, float s, const float4& w) {
    a.x = fmaf(s, w.x, a.x);
    a.y = fmaf(s, w.y, a.y);
    a.z = fmaf(s, w.z, a.z);
    a.w = fmaf(s, w.w, a.w);
}

// Shared-memory pool reused across phases (~67.7KB)
struct SMem {
    float w[2][3200];     // staging tiles (W / g / go1)
    float adjW[4160];     // adjW tile: written P1, read P2 (coop) / staged (fallback)
    float pool[4160];     // P0: gt+ln; P1: adjS then ax+go; P2: ax
    float q[1600];        // P0: xn dbuf; P1: q tiles
    float red[5][64];
    float was[5], aspb[20];
    float w1[100], w2[100], g1row[16];
    float mean[16], rinv[16];
};

//============================ PHASE 0: LN + g + q/k ==========================
__device__ __forceinline__ void phase0(
    SMem& sm, int blk, int t,
    const float* __restrict__ x, const float* __restrict__ ln_a,
    const float* __restrict__ ln_b, const float* __restrict__ Wxx_w,
    const float* __restrict__ Wxx_b, const float* __restrict__ q_w,
    const float* __restrict__ q_b, const float* __restrict__ k_w,
    const float* __restrict__ k_b, const float* __restrict__ amask,
    float* __restrict__ g, float* __restrict__ qt, float* __restrict__ ktb,
    float* __restrict__ aspect_raw)
{
    const int r0 = blk * 16;
    const int wid = t >> 6, lane = t & 63;
    float* s_gt = sm.pool;            // 1600
    float* s_ln = sm.pool + 1600;     // 1536
    float* s_xn0 = sm.q;              // 576
    float* s_xn1 = sm.q + 576;        // 576

    if (t < 192) {
        ((float4*)s_ln)[t] = ((const float4*)ln_a)[t];
        ((float4*)(s_ln + 768))[t] = ((const float4*)ln_b)[t];
    }
    for (int rr = wid * 4; rr < wid * 4 + 4; ++rr) {
        const float* xr = x + (size_t)(r0 + rr) * CD;
        float xv[12];
        float s = 0.f;
#pragma unroll
        for (int m = 0; m < 12; ++m) { xv[m] = xr[lane + 64 * m]; s += xv[m]; }
#pragma unroll
        for (int o = 32; o; o >>= 1) s += __shfl_xor(s, o);
        float mean = s * (1.0f / 768.0f);
        float sq = 0.f;
#pragma unroll
        for (int m = 0; m < 12; ++m) { float d = xv[m] - mean; sq = fmaf(d, d, sq); }
#pragma unroll
        for (int o = 32; o; o >>= 1) sq += __shfl_xor(sq, o);
        if (lane == 0) {
            sm.mean[rr] = mean;
            sm.rinv[rr] = 1.0f / (sqrtf(sq * (1.0f / 767.0f)) + 1e-6f);
        }
    }

    const float4* wsrc = (const float4*)Wxx_w;
    float4 w0 = wsrc[t], w1 = wsrc[t + 256], w2 = wsrc[t + 512], w3;
    if (t < 32) w3 = wsrc[t + 768];
    const int rA = t >> 5, cA = t & 31;
    float xa = x[(size_t)(r0 + rA) * CD + cA];
    float xb = x[(size_t)(r0 + rA + 8) * CD + cA];

    __syncthreads();   // s_ln + stats visible

    {
        float4* d4 = (float4*)sm.w[0];
        d4[t] = w0; d4[t + 256] = w1; d4[t + 512] = w2;
        if (t < 32) d4[t + 768] = w3;
        float la = s_ln[cA], lbv = s_ln[768 + cA];
        s_xn0[rA * 36 + cA] = fmaf(la, (xa - sm.mean[rA]) * sm.rinv[rA], lbv);
        s_xn0[(rA + 8) * 36 + cA] = fmaf(la, (xb - sm.mean[rA + 8]) * sm.rinv[rA + 8], lbv);
    }
    __syncthreads();

    const int cg2 = t % 25, rg = t / 25;
    const int c = cg2 * 4;
    float4 acc0 = make_float4(0.f, 0.f, 0.f, 0.f);
    float4 acc1 = make_float4(0.f, 0.f, 0.f, 0.f);

    for (int kt = 0; kt < 24; ++kt) {
        if (kt < 23) {
            const float4* ws = wsrc + (size_t)(kt + 1) * 800;
            w0 = ws[t]; w1 = ws[t + 256]; w2 = ws[t + 512];
            if (t < 32) w3 = ws[t + 768];
            int gc = (kt + 1) * 32 + cA;
            xa = x[(size_t)(r0 + rA) * CD + gc];
            xb = x[(size_t)(r0 + rA + 8) * CD + gc];
        }
        if (t < 200) {
            const float* wb = sm.w[kt & 1];
            const float* xbuf = (kt & 1) ? s_xn1 : s_xn0;
#pragma unroll 2
            for (int kk = 0; kk < 32; kk += 4) {
                float4 a0 = *(const float4*)&xbuf[(rg * 2 + 0) * 36 + kk];
                float4 a1 = *(const float4*)&xbuf[(rg * 2 + 1) * 36 + kk];
                float4 v0 = *(const float4*)&wb[(kk + 0) * 100 + c];
                float4 v1 = *(const float4*)&wb[(kk + 1) * 100 + c];
                float4 v2 = *(const float4*)&wb[(kk + 2) * 100 + c];
                float4 v3 = *(const float4*)&wb[(kk + 3) * 100 + c];
                fma4(acc0, a0.x, v0); fma4(acc0, a0.y, v1); fma4(acc0, a0.z, v2); fma4(acc0, a0.w, v3);
                fma4(acc1, a1.x, v0); fma4(acc1, a1.y, v1); fma4(acc1, a1.z, v2); fma4(acc1, a1.w, v3);
            }
        }
        if (kt < 23) {
            float4* d4 = (float4*)sm.w[(kt + 1) & 1];
            d4[t] = w0; d4[t + 256] = w1; d4[t + 512] = w2;
            if (t < 32) d4[t + 768] = w3;
            int gc = (kt + 1) * 32 + cA;
            float la = s_ln[gc], lbv = s_ln[768 + gc];
            float* xd = ((kt + 1) & 1) ? s_xn1 : s_xn0;
            xd[rA * 36 + cA] = fmaf(la, (xa - sm.mean[rA]) * sm.rinv[rA], lbv);
            xd[(rA + 8) * 36 + cA] = fmaf(la, (xb - sm.mean[rA + 8]) * sm.rinv[rA + 8], lbv);
        }
        __syncthreads();
    }

    if (t < 200) {
        float4 bias = *(const float4*)&Wxx_b[c];
        float4 rv0, rv1;
        rv0.x = acc0.x + bias.x; rv0.y = acc0.y + bias.y; rv0.z = acc0.z + bias.z; rv0.w = acc0.w + bias.w;
        rv1.x = acc1.x + bias.x; rv1.y = acc1.y + bias.y; rv1.z = acc1.z + bias.z; rv1.w = acc1.w + bias.w;
        float4 rv[2] = { rv0, rv1 };
#pragma unroll
        for (int q = 0; q < 2; ++q) {
            int row = r0 + rg * 2 + q;
            *(float4*)&g[(size_t)row * CATT + c] = rv[q];
            *(float4*)&s_gt[(rg * 2 + q) * 100 + c] = rv[q];
            float m = amask[row];
            if (m != 0.f) {
                int b = row >> 8;
                atomicAdd(&aspect_raw[b * CATT + c + 0], m * rv[q].x);
                atomicAdd(&aspect_raw[b * CATT + c + 1], m * rv[q].y);
                atomicAdd(&aspect_raw[b * CATT + c + 2], m * rv[q].z);
                atomicAdd(&aspect_raw[b * CATT + c + 3], m * rv[q].w);
            }
        }
    }

    // q/k GEMMs: 10 pipelined 20x100 tiles (0-4 q_w, 5-9 k_w)
    const float4* qw4 = (const float4*)q_w;
    const float4* kw4 = (const float4*)k_w;
    float4 sA = qw4[t], sB;
    if (t < 244) sB = qw4[t + 256];
    __syncthreads();   // s_gt visible; main-loop LDS traffic done
    {
        float4* d4 = (float4*)sm.w[0];
        d4[t] = sA; if (t < 244) d4[t + 256] = sB;
    }
    __syncthreads();

    float4 p0 = make_float4(0.f, 0.f, 0.f, 0.f);
    float4 p1 = make_float4(0.f, 0.f, 0.f, 0.f);
    for (int tau = 0; tau < 10; ++tau) {
        if (tau < 9) {
            const float4* src = (tau + 1 < 5) ? qw4 + (size_t)(tau + 1) * 500
                                              : kw4 + (size_t)(tau - 4) * 500;
            sA = src[t]; if (t < 244) sB = src[t + 256];
        }
        if (t < 200) {
            const float* wb = sm.w[tau & 1];
            const int kb = (tau % 5) * 20;
#pragma unroll 2
            for (int kk = 0; kk < 20; kk += 4) {
                float4 a0 = *(const float4*)&s_gt[(rg * 2 + 0) * 100 + kb + kk];
                float4 a1 = *(const float4*)&s_gt[(rg * 2 + 1) * 100 + kb + kk];
                float4 v0 = *(const float4*)&wb[(kk + 0) * 100 + c];
                float4 v1 = *(const float4*)&wb[(kk + 1) * 100 + c];
                float4 v2 = *(const float4*)&wb[(kk + 2) * 100 + c];
                float4 v3 = *(const float4*)&wb[(kk + 3) * 100 + c];
                fma4(p0, a0.x, v0); fma4(p0, a0.y, v1); fma4(p0, a0.z, v2); fma4(p0, a0.w, v3);
                fma4(p1, a1.x, v0); fma4(p1, a1.y, v1); fma4(p1, a1.z, v2); fma4(p1, a1.w, v3);
            }
            if (tau == 4 || tau == 9) {
                const float* bb = (tau == 4) ? q_b : k_b;
                float* outp = (tau == 4) ? qt : ktb;
                float4 bias = *(const float4*)&bb[c];
                p0.x += bias.x; p0.y += bias.y; p0.z += bias.z; p0.w += bias.w;
                p1.x += bias.x; p1.y += bias.y; p1.z += bias.z; p1.w += bias.w;
                const int h = c / CDK, d = c % CDK;
                float4 rv[2] = { p0, p1 };
#pragma unroll
                for (int q = 0; q < 2; ++q) {
                    int row = r0 + rg * 2 + q;
                    int bidx = row >> 8, l = row & 255;
                    *(float4*)&outp[((size_t)(bidx * CH + h) * CL + l) * CDK + d] = rv[q];
                }
                p0 = make_float4(0.f, 0.f, 0.f, 0.f);
                p1 = make_float4(0.f, 0.f, 0.f, 0.f);
            }
        }
        if (tau < 9) {
            float4* d4 = (float4*)sm.w[(tau + 1) & 1];
            d4[t] = sA; if (t < 244) d4[t + 256] = sB;
        }
        __syncthreads();
    }
}

//====================== PHASE 1: softmax + GCN0 + rank-1 =====================
// adjW tile -> sm.adjW always; also -> adjW_global if non-null (fallback path).
__device__ __forceinline__ void phase1(
    SMem& sm, int blk, int t,
    const float* __restrict__ qt, const float* __restrict__ ktb,
    const float* __restrict__ aspect_raw, const float* __restrict__ amask,
    const float* __restrict__ dense_w, const float* __restrict__ dense_b,
    const float* __restrict__ bias_m, const int* __restrict__ src_mask,
    const float* __restrict__ shortm, const float* __restrict__ Wx_w,
    const float* __restrict__ g, const float* __restrict__ W_w,
    const float* __restrict__ W_b, float* __restrict__ go1,
    float* __restrict__ t1, float* __restrict__ t2, float* __restrict__ gW2S,
    float* __restrict__ adjW_global)
{
    constexpr int ICH = 16;
    const int b = blk >> 4, ic = blk & 15;
    const int i0 = ic * ICH;
    const int lane = t & 63, wid = t >> 6;
    const int j = t;

    if (t < 5) {
        float s = 0.f;
        for (int k2 = 0; k2 < 5; ++k2) s += Wx_w[t * 5 + k2];
        sm.was[t] = s;
    }
    if (t < 100) {
        float a = 0.f, c2 = 0.f;
#pragma unroll
        for (int h = 0; h < 5; ++h) {
            a += Wx_w[(5 + t) * 5 + h];
            c2 += Wx_w[(105 + t) * 5 + h];
        }
        sm.w1[t] = a; sm.w2[t] = c2;
    }
    float wn = 0.f;
    if (t < 64) {
        float4 mv = ((const float4*)amask)[b * 64 + t];
        wn = mv.x + mv.y + mv.z + mv.w;
#pragma unroll
        for (int o = 32; o; o >>= 1) wn += __shfl_xor(wn, o);
    }
    if (t < 20) {
        float a = 0.f;
        for (int d = 0; d < CATT; ++d)
            a = fmaf(aspect_raw[b * CATT + d], dense_w[d * CDK + t], a);
        sm.aspb[t] = a / wn + dense_b[t];
    }
    {
        const float* qbase = qt + (size_t)b * CH * CL * CDK + (size_t)i0 * CDK;
        for (int i = t; i < CH * 320; i += 256) {
            int h = i / 320, r = i % 320;
            sm.q[i] = qbase[(size_t)h * CL * CDK + r];
        }
    }

    const bool masked = (src_mask[b * CL + j] == 0);
    const float bm = bias_m[0];
    const float rs20 = 0.223606797749978969f;

    float smv[ICH];
#pragma unroll
    for (int ii = 0; ii < ICH; ++ii)
        smv[ii] = shortm[(size_t)(b * CL + i0 + ii) * CL + j];

    float accS[ICH], accW[ICH];
#pragma unroll
    for (int ii = 0; ii < ICH; ++ii) { accS[ii] = 0.f; accW[ii] = 0.f; }

    __syncthreads();

    for (int h = 0; h < CH; ++h) {
        float4 kr[5];
        const float* kp = ktb + ((size_t)(b * CH + h) * CL + j) * CDK;
#pragma unroll
        for (int m = 0; m < 5; ++m) kr[m] = *(const float4*)(kp + 4 * m);
        const float was_h = sm.was[h];
        float s = bm;
#pragma unroll
        for (int m = 0; m < 5; ++m) {
            s = fmaf(sm.aspb[4 * m + 0], kr[m].x, s);
            s = fmaf(sm.aspb[4 * m + 1], kr[m].y, s);
            s = fmaf(sm.aspb[4 * m + 2], kr[m].z, s);
            s = fmaf(sm.aspb[4 * m + 3], kr[m].w, s);
        }
        const float aspsc = tanhf(s);

        float pv[ICH];
#pragma unroll
        for (int ii = 0; ii < ICH; ++ii) {
            const float* qrow = &sm.q[h * 320 + ii * CDK];
            float sc = 0.f;
#pragma unroll
            for (int m = 0; m < 5; ++m) {
                float4 q4 = *(const float4*)(qrow + 4 * m);
                sc = fmaf(q4.x, kr[m].x, sc);
                sc = fmaf(q4.y, kr[m].y, sc);
                sc = fmaf(q4.z, kr[m].z, sc);
                sc = fmaf(q4.w, kr[m].w, sc);
            }
            sc = fmaf(sc, rs20, aspsc) + smv[ii];
            float p = masked ? 0.f : __expf(sc);
            pv[ii] = p;
            float ssum = p;
#pragma unroll
            for (int o = 32; o; o >>= 1) ssum += __shfl_xor(ssum, o);
            if (lane == 0) sm.red[h][ii * 4 + wid] = ssum;
        }
        __syncthreads();
#pragma unroll
        for (int ii = 0; ii < ICH; ++ii) {
            float tot = sm.red[h][ii * 4 + 0] + sm.red[h][ii * 4 + 1] +
                        sm.red[h][ii * 4 + 2] + sm.red[h][ii * 4 + 3];
            float pn = pv[ii] * __frcp_rn(tot);
            accS[ii] += pn;
            accW[ii] = fmaf(was_h, pn, accW[ii]);
        }
    }

#pragma unroll
    for (int ii = 0; ii < ICH; ++ii) {
        sm.adjW[ii * 260 + j] = accW[ii];
        sm.pool[ii * 260 + j] = accS[ii];
    }
    if (adjW_global) {
#pragma unroll
        for (int ii = 0; ii < ICH; ++ii)
            adjW_global[(size_t)(b * CL + i0 + ii) * CL + j] = accW[ii];
    }

    // GEMM1: Ax = adjS_tile @ g (8 pipelined 32x100 tiles)
    const int cg2 = t % 25, rg = t / 25;
    const int c = cg2 * 4;
    const float4* g4 = (const float4*)g + (size_t)b * 6400;
    float4 sA = g4[t], sB = g4[t + 256], sC = g4[t + 512], sD;
    if (t < 32) sD = g4[t + 768];
    {
        float4* d4 = (float4*)sm.w[0];
        d4[t] = sA; d4[t + 256] = sB; d4[t + 512] = sC;
        if (t < 32) d4[t + 768] = sD;
    }
    __syncthreads();

    float4 acc0 = make_float4(0.f, 0.f, 0.f, 0.f);
    float4 acc1 = make_float4(0.f, 0.f, 0.f, 0.f);
    for (int jt = 0; jt < 8; ++jt) {
        if (jt < 7) {
            const float4* src = g4 + (size_t)(jt + 1) * 800;
            sA = src[t]; sB = src[t + 256]; sC = src[t + 512];
            if (t < 32) sD = src[t + 768];
        }
        if (t < 200) {
            const float* wb = sm.w[jt & 1];
#pragma unroll 2
            for (int kk = 0; kk < 32; kk += 4) {
                float4 a0 = *(const float4*)&sm.pool[(rg * 2 + 0) * 260 + jt * 32 + kk];
                float4 a1 = *(const float4*)&sm.pool[(rg * 2 + 1) * 260 + jt * 32 + kk];
                float4 v0 = *(const float4*)&wb[(kk + 0) * 100 + c];
                float4 v1 = *(const float4*)&wb[(kk + 1) * 100 + c];
                float4 v2 = *(const float4*)&wb[(kk + 2) * 100 + c];
                float4 v3 = *(const float4*)&wb[(kk + 3) * 100 + c];
                fma4(acc0, a0.x, v0); fma4(acc0, a0.y, v1); fma4(acc0, a0.z, v2); fma4(acc0, a0.w, v3);
                fma4(acc1, a1.x, v0); fma4(acc1, a1.y, v1); fma4(acc1, a1.z, v2); fma4(acc1, a1.w, v3);
            }
        }
        if (jt < 7) {
            float4* d4 = (float4*)sm.w[(jt + 1) & 1];
            d4[t] = sA; d4[t + 256] = sB; d4[t + 512] = sC;
            if (t < 32) d4[t + 768] = sD;
        }
        __syncthreads();
    }

    float* s_ax = sm.pool;
    if (t < 200) {
        float4 r;
        r.x = acc0.x * 0.2f; r.y = acc0.y * 0.2f; r.z = acc0.z * 0.2f; r.w = acc0.w * 0.2f;
        *(float4*)&s_ax[(rg * 2 + 0) * 108 + c] = r;
        r.x = acc1.x * 0.2f; r.y = acc1.y * 0.2f; r.z = acc1.z * 0.2f; r.w = acc1.w * 0.2f;
        *(float4*)&s_ax[(rg * 2 + 1) * 108 + c] = r;
    }
    const float4* ww4 = (const float4*)W_w;
    sA = ww4[t]; if (t < 244) sB = ww4[t + 256];
    {
        float4* d4 = (float4*)sm.w[0];
        d4[t] = sA; if (t < 244) d4[t + 256] = sB;
    }
    __syncthreads();

    float4 o0 = make_float4(0.f, 0.f, 0.f, 0.f);
    float4 o1 = make_float4(0.f, 0.f, 0.f, 0.f);
    for (int wt = 0; wt < 5; ++wt) {
        if (wt < 4) {
            const float4* src = ww4 + (size_t)(wt + 1) * 500;
            sA = src[t]; if (t < 244) sB = src[t + 256];
        }
        if (t < 200) {
            const float* wb = sm.w[wt & 1];
            const int kb = wt * 20;
#pragma unroll 2
            for (int kk = 0; kk < 20; kk += 4) {
                float4 a0 = *(const float4*)&s_ax[(rg * 2 + 0) * 108 + kb + kk];
                float4 a1 = *(const float4*)&s_ax[(rg * 2 + 1) * 108 + kb + kk];
                float4 v0 = *(const float4*)&wb[(kk + 0) * 100 + c];
                float4 v1 = *(const float4*)&wb[(kk + 1) * 100 + c];
                float4 v2 = *(const float4*)&wb[(kk + 2) * 100 + c];
                float4 v3 = *(const float4*)&wb[(kk + 3) * 100 + c];
                fma4(o0, a0.x, v0); fma4(o0, a0.y, v1); fma4(o0, a0.z, v2); fma4(o0, a0.w, v3);
                fma4(o1, a1.x, v0); fma4(o1, a1.y, v1); fma4(o1, a1.z, v2); fma4(o1, a1.w, v3);
            }
        }
        if (wt < 4) {
            float4* d4 = (float4*)sm.w[(wt + 1) & 1];
            d4[t] = sA; if (t < 244) d4[t + 256] = sB;
        }
        __syncthreads();
    }

    float* s_go = sm.pool + 1728;
    if (t < 200) {
        float4 bias = *(const float4*)&W_b[c];
        o0.x = fmaxf(o0.x + bias.x, 0.f); o0.y = fmaxf(o0.y + bias.y, 0.f);
        o0.z = fmaxf(o0.z + bias.z, 0.f); o0.w = fmaxf(o0.w + bias.w, 0.f);
        o1.x = fmaxf(o1.x + bias.x, 0.f); o1.y = fmaxf(o1.y + bias.y, 0.f);
        o1.z = fmaxf(o1.z + bias.z, 0.f); o1.w = fmaxf(o1.w + bias.w, 0.f);
        *(float4*)&go1[(size_t)(b * CL + i0 + rg * 2 + 0) * CATT + c] = o0;
        *(float4*)&go1[(size_t)(b * CL + i0 + rg * 2 + 1) * CATT + c] = o1;
        *(float4*)&s_go[(rg * 2 + 0) * 104 + c] = o0;
        *(float4*)&s_go[(rg * 2 + 1) * 104 + c] = o1;
    }
    __syncthreads();

    if (t < 128) {
        int r = t >> 3, seg = t & 7;
        int e0 = seg * 13, e1 = e0 + 13 < 100 ? e0 + 13 : 100;
        float a = 0.f, c2 = 0.f;
        for (int e = e0; e < e1; ++e) {
            float v = s_go[r * 104 + e];
            a = fmaf(v, sm.w1[e], a);
            c2 = fmaf(v, sm.w2[e], c2);
        }
        a += __shfl_xor(a, 1); a += __shfl_xor(a, 2); a += __shfl_xor(a, 4);
        c2 += __shfl_xor(c2, 1); c2 += __shfl_xor(c2, 2); c2 += __shfl_xor(c2, 4);
        if (seg == 0) {
            sm.g1row[r] = a;
            gW2S[b * CL + i0 + r] = c2;
        }
    }
    __syncthreads();

    if (t < 100) {
        float a = 0.f, s2 = 0.f;
#pragma unroll
        for (int r = 0; r < 16; ++r) {
            float v = s_go[r * 104 + t];
            a = fmaf(sm.g1row[r], v, a);
            s2 += v;
        }
        atomicAdd(&t1[b * CATT + t], a);
        atomicAdd(&t2[b * CATT + t], s2);
    }
}

//====================== PHASE 2: GCN1 + masked pooling =======================
// Reads sm.adjW (populated by phase1 in coop, or staged by the wrapper).
__device__ __forceinline__ void phase2(
    SMem& sm, int blk, int t,
    const float* __restrict__ go1, const float* __restrict__ W_w,
    const float* __restrict__ W_b, const float* __restrict__ t1,
    const float* __restrict__ t2, const float* __restrict__ gW2S,
    const float* __restrict__ Wx_b, const float* __restrict__ amask,
    float* __restrict__ out1_raw)
{
    const int b = blk >> 4, ic = blk & 15;
    const int i0 = ic * 16;
    const int cg2 = t % 25, rg = t / 25;
    const int c = cg2 * 4;

    const float4* g4 = (const float4*)go1 + (size_t)b * 6400;
    float4 sA = g4[t], sB = g4[t + 256], sC = g4[t + 512], sD;
    if (t < 32) sD = g4[t + 768];
    {
        float4* d4 = (float4*)sm.w[0];
        d4[t] = sA; d4[t + 256] = sB; d4[t + 512] = sC;
        if (t < 32) d4[t + 768] = sD;
    }
    __syncthreads();

    float4 acc0 = make_float4(0.f, 0.f, 0.f, 0.f);
    float4 acc1 = make_float4(0.f, 0.f, 0.f, 0.f);
    for (int jt = 0; jt < 8; ++jt) {
        if (jt < 7) {
            const float4* src = g4 + (size_t)(jt + 1) * 800;
            sA = src[t]; sB = src[t + 256]; sC = src[t + 512];
            if (t < 32) sD = src[t + 768];
        }
        if (t < 200) {
            const float* wb = sm.w[jt & 1];
#pragma unroll 2
            for (int kk = 0; kk < 32; kk += 4) {
                float4 a0 = *(const float4*)&sm.adjW[(rg * 2 + 0) * 260 + jt * 32 + kk];
                float4 a1 = *(const float4*)&sm.adjW[(rg * 2 + 1) * 260 + jt * 32 + kk];
                float4 v0 = *(const float4*)&wb[(kk + 0) * 100 + c];
                float4 v1 = *(const float4*)&wb[(kk + 1) * 100 + c];
                float4 v2 = *(const float4*)&wb[(kk + 2) * 100 + c];
                float4 v3 = *(const float4*)&wb[(kk + 3) * 100 + c];
                fma4(acc0, a0.x, v0); fma4(acc0, a0.y, v1); fma4(acc0, a0.z, v2); fma4(acc0, a0.w, v3);
                fma4(acc1, a1.x, v0); fma4(acc1, a1.y, v1); fma4(acc1, a1.z, v2); fma4(acc1, a1.w, v3);
            }
        }
        if (jt < 7) {
            float4* d4 = (float4*)sm.w[(jt + 1) & 1];
            d4[t] = sA; d4[t + 256] = sB; d4[t + 512] = sC;
            if (t < 32) d4[t + 768] = sD;
        }
        __syncthreads();
    }

    float* s_ax = sm.pool;
    if (t < 200) {
        float wxbs = Wx_b[0] + Wx_b[1] + Wx_b[2] + Wx_b[3] + Wx_b[4];
        float4 t1v = *(const float4*)&t1[b * CATT + c];
        float4 t2v = *(const float4*)&t2[b * CATT + c];
        float gw0 = gW2S[b * CL + i0 + rg * 2 + 0] + wxbs;
        float gw1 = gW2S[b * CL + i0 + rg * 2 + 1] + wxbs;
        float4 r;
        r.x = (acc0.x + t1v.x + gw0 * t2v.x) * 0.2f;
        r.y = (acc0.y + t1v.y + gw0 * t2v.y) * 0.2f;
        r.z = (acc0.z + t1v.z + gw0 * t2v.z) * 0.2f;
        r.w = (acc0.w + t1v.w + gw0 * t2v.w) * 0.2f;
        *(float4*)&s_ax[(rg * 2 + 0) * 108 + c] = r;
        r.x = (acc1.x + t1v.x + gw1 * t2v.x) * 0.2f;
        r.y = (acc1.y + t1v.y + gw1 * t2v.y) * 0.2f;
        r.z = (acc1.z + t1v.z + gw1 * t2v.z) * 0.2f;
        r.w = (acc1.w + t1v.w + gw1 * t2v.w) * 0.2f;
        *(float4*)&s_ax[(rg * 2 + 1) * 108 + c] = r;
    }
    const float4* ww4 = (const float4*)W_w;
    sA = ww4[t]; if (t < 244) sB = ww4[t + 256];
    {
        float4* d4 = (float4*)sm.w[0];
        d4[t] = sA; if (t < 244) d4[t + 256] = sB;
    }
    __syncthreads();

    float4 o0 = make_float4(0.f, 0.f, 0.f, 0.f);
    float4 o1 = make_float4(0.f, 0.f, 0.f, 0.f);
    for (int wt = 0; wt < 5; ++wt) {
        if (wt < 4) {
            const float4* src = ww4 + (size_t)(wt + 1) * 500;
            sA = src[t]; if (t < 244) sB = src[t + 256];
        }
        if (t < 200) {
            const float* wb = sm.w[wt & 1];
            const int kb = wt * 20;
#pragma unroll 2
            for (int kk = 0; kk < 20; kk += 4) {
                float4 a0 = *(const float4*)&s_ax[(rg * 2 + 0) * 108 + kb + kk];
                float4 a1 = *(const float4*)&s_ax[(rg * 2 + 1) * 108 + kb + kk];
                float4 v0 = *(const float4*)&wb[(kk + 0) * 100 + c];
                float4 v1 = *(const float4*)&wb[(kk + 1) * 100 + c];
                float4 v2 = *(const float4*)&wb[(kk + 2) * 100 + c];
                float4 v3 = *(const float4*)&wb[(kk + 3) * 100 + c];
                fma4(o0, a0.x, v0); fma4(o0, a0.y, v1); fma4(o0, a0.z, v2); fma4(o0, a0.w, v3);
                fma4(o1, a1.x, v0); fma4(o1, a1.y, v1); fma4(o1, a1.z, v2); fma4(o1, a1.w, v3);
            }
        }
        if (wt < 4) {
            float4* d4 = (float4*)sm.w[(wt + 1) & 1];
            d4[t] = sA; if (t < 244) d4[t + 256] = sB;
        }
        __syncthreads();
    }

    if (t < 200) {
        float4 bias = *(const float4*)&W_b[c];
        o0.x = fmaxf(o0.x + bias.x, 0.f); o0.y = fmaxf(o0.y + bias.y, 0.f);
        o0.z = fmaxf(o0.z + bias.z, 0.f); o0.w = fmaxf(o0.w + bias.w, 0.f);
        o1.x = fmaxf(o1.x + bias.x, 0.f); o1.y = fmaxf(o1.y + bias.y, 0.f);
        o1.z = fmaxf(o1.z + bias.z, 0.f); o1.w = fmaxf(o1.w + bias.w, 0.f);
        float4 ov[2] = { o0, o1 };
#pragma unroll
        for (int q = 0; q < 2; ++q) {
            int row = b * CL + i0 + rg * 2 + q;
            float m = amask[row];
            if (m != 0.f) {
                atomicAdd(&out1_raw[b * CATT + c + 0], m * ov[q].x);
                atomicAdd(&out1_raw[b * CATT + c + 1], m * ov[q].y);
                atomicAdd(&out1_raw[b * CATT + c + 2], m * ov[q].z);
                atomicAdd(&out1_raw[b * CATT + c + 3], m * ov[q].w);
            }
        }
    }
}

//============================ PHASE 3: classifier ============================
__device__ __forceinline__ void phase3(
    int blk, int t, const float* __restrict__ out1_raw,
    const float* __restrict__ amask, const float* __restrict__ clf_w,
    const float* __restrict__ clf_b, float* __restrict__ out)
{
    if (blk < 32 && t < 64) {
        const int b = blk;
        float4 mv = ((const float4*)amask)[b * 64 + t];
        float wn = mv.x + mv.y + mv.z + mv.w;
#pragma unroll
        for (int o = 32; o; o >>= 1) wn += __shfl_xor(wn, o);
        if (t < 3) {
            float rwn = 1.f / wn;
            float a = clf_b[t];
            for (int d = 0; d < CATT; ++d)
                a = fmaf(out1_raw[b * CATT + d] * rwn, clf_w[d * 3 + t], a);
            out[b * 3 + t] = a;
        }
    }
}

//===================== cooperative mega-kernel (preferred) ===================
__global__ __launch_bounds__(256, 2) void k_all(
    const float* x, const float* ln_a, const float* ln_b, const float* Wxx_w,
    const float* Wxx_b, const float* q_w, const float* q_b, const float* k_w,
    const float* k_b, const float* amask, const int* src_mask,
    const float* shortm, const float* dense_w, const float* dense_b,
    const float* bias_m, const float* Wx_w, const float* Wx_b,
    const float* W_w, const float* W_b, const float* clf_w,
    const float* clf_b, float* g, float* qt, float* ktb, float* go1,
    float* aspect_raw, float* t1, float* t2, float* out1_raw, float* gW2S,
    float* out)
{
    __shared__ SMem sm;
    const int t = threadIdx.x, blk = blockIdx.x;
    cg::grid_group grid = cg::this_grid();

    phase0(sm, blk, t, x, ln_a, ln_b, Wxx_w, Wxx_b, q_w, q_b, k_w, k_b,
           amask, g, qt, ktb, aspect_raw);
    __threadfence();
    grid.sync();
    phase1(sm, blk, t, qt, ktb, aspect_raw, amask, dense_w, dense_b, bias_m,
           src_mask, shortm, Wx_w, g, W_w, W_b, go1, t1, t2, gW2S, nullptr);
    __threadfence();
    grid.sync();
    phase2(sm, blk, t, go1, W_w, W_b, t1, t2, gW2S, Wx_b, amask, out1_raw);
    __threadfence();
    grid.sync();
    phase3(blk, t, out1_raw, amask, clf_w, clf_b, out);
}

//===================== fallback wrappers (r5 structure) ======================
__global__ __launch_bounds__(256, 2) void kP0(
    const float* x, const float* ln_a, const float* ln_b, const float* Wxx_w,
    const float* Wxx_b, const float* q_w, const float* q_b, const float* k_w,
    const float* k_b, const float* amask, float* g, float* qt, float* ktb,
    float* aspect_raw)
{
    __shared__ SMem sm;
    phase0(sm, blockIdx.x, threadIdx.x, x, ln_a, ln_b, Wxx_w, Wxx_b,
           q_w, q_b, k_w, k_b, amask, g, qt, ktb, aspect_raw);
}

__global__ __launch_bounds__(256, 2) void kP1(
    const float* qt, const float* ktb, const float* aspect_raw,
    const float* amask, const float* dense_w, const float* dense_b,
    const float* bias_m, const int* src_mask, const float* shortm,
    const float* Wx_w, const float* g, const float* W_w, const float* W_b,
    float* go1, float* t1, float* t2, float* gW2S, float* adjW)
{
    __shared__ SMem sm;
    phase1(sm, blockIdx.x, threadIdx.x, qt, ktb, aspect_raw, amask, dense_w,
           dense_b, bias_m, src_mask, shortm, Wx_w, g, W_w, W_b, go1,
           t1, t2, gW2S, adjW);
}

__global__ __launch_bounds__(256, 2) void kP2(
    const float* adjW, const float* go1, const float* W_w, const float* W_b,
    const float* t1, const float* t2, const float* gW2S, const float* Wx_b,
    const float* amask, float* out1_raw)
{
    __shared__ SMem sm;
    const int t = threadIdx.x;
    const int b = blockIdx.x >> 4, ic = blockIdx.x & 15;
    {
        const float4* asrc = (const float4*)adjW + (size_t)(b * CL + ic * 16) * 64;
#pragma unroll
        for (int m = 0; m < 4; ++m) {
            int i = t + 256 * m;
            int row = i >> 6, c4 = i & 63;
            *(float4*)&sm.adjW[row * 260 + c4 * 4] = asrc[i];
        }
    }
    __syncthreads();
    phase2(sm, blockIdx.x, t, go1, W_w, W_b, t1, t2, gW2S, Wx_b, amask, out1_raw);
}

__global__ __launch_bounds__(64) void kP3(
    const float* out1_raw, const float* amask, const float* clf_w,
    const float* clf_b, float* out)
{
    phase3(blockIdx.x, threadIdx.x, out1_raw, amask, clf_w, clf_b, out);
}

// ---------------------------------------------------------------------------
extern "C" void kernel_launch(void* const* d_in, const int* in_sizes, int n_in,
                              void* d_out, int out_size, void* d_ws, size_t ws_size,
                              hipStream_t stream) {
    const float* seq     = (const float*)d_in[0];
    const int*   srcm    = (const int*)d_in[1];
    const float* amask   = (const float*)d_in[2];
    const float* shortm  = (const float*)d_in[3];
    const float* ln_a    = (const float*)d_in[4];
    const float* ln_b    = (const float*)d_in[5];
    const float* Wxx_w   = (const float*)d_in[6];
    const float* Wxx_b   = (const float*)d_in[7];
    const float* q_w     = (const float*)d_in[8];
    const float* q_b     = (const float*)d_in[9];
    const float* k_w     = (const float*)d_in[10];
    const float* k_b     = (const float*)d_in[11];
    const float* dense_w = (const float*)d_in[12];
    const float* dense_b = (const float*)d_in[13];
    const float* bias_m  = (const float*)d_in[14];
    const float* W_w     = (const float*)d_in[15];
    const float* W_b     = (const float*)d_in[16];
    const float* Wx_w    = (const float*)d_in[17];
    const float* Wx_b    = (const float*)d_in[18];
    const float* clf_w   = (const float*)d_in[19];
    const float* clf_b   = (const float*)d_in[20];
    float* out = (float*)d_out;

    float* ws         = (float*)d_ws;
    float* g          = ws;
    float* qt         = g + 819200;
    float* ktb        = qt + 819200;
    float* go1        = ktb + 819200;
    float* adjW       = go1 + 819200;        // fallback only
    float* aspect_raw = adjW + 2097152;
    float* t1         = aspect_raw + 3200;
    float* t2         = t1 + 3200;
    float* out1_raw   = t2 + 3200;
    float* gW2S       = out1_raw + 3200;

    hipMemsetAsync(aspect_raw, 0, 4 * 3200 * sizeof(float), stream);

    // Coop only if the runtime proves 512 blocks can be co-resident.
    int maxb = 0;
    hipError_t qerr = hipOccupancyMaxActiveBlocksPerMultiprocessor(
        &maxb, reinterpret_cast<const void*>(k_all), 256, 0);
    bool coop = (qerr == hipSuccess && maxb >= 2);

    if (coop) {
        void* args[] = {
            (void*)&seq, (void*)&ln_a, (void*)&ln_b, (void*)&Wxx_w, (void*)&Wxx_b,
            (void*)&q_w, (void*)&q_b, (void*)&k_w, (void*)&k_b, (void*)&amask,
            (void*)&srcm, (void*)&shortm, (void*)&dense_w, (void*)&dense_b,
            (void*)&bias_m, (void*)&Wx_w, (void*)&Wx_b, (void*)&W_w, (void*)&W_b,
            (void*)&clf_w, (void*)&clf_b, (void*)&g, (void*)&qt, (void*)&ktb,
            (void*)&go1, (void*)&aspect_raw, (void*)&t1, (void*)&t2,
            (void*)&out1_raw, (void*)&gW2S, (void*)&out
        };
        hipError_t lerr = hipLaunchCooperativeKernel(
            (void*)k_all, dim3(512), dim3(256), args, 0, stream);
        if (lerr != hipSuccess) { (void)hipGetLastError(); coop = false; }
    }
    if (!coop) {
        hipLaunchKernelGGL(kP0, dim3(512), dim3(256), 0, stream, seq, ln_a, ln_b,
                           Wxx_w, Wxx_b, q_w, q_b, k_w, k_b, amask, g, qt, ktb, aspect_raw);
        hipLaunchKernelGGL(kP1, dim3(512), dim3(256), 0, stream, qt, ktb, aspect_raw,
                           amask, dense_w, dense_b, bias_m, srcm, shortm, Wx_w,
                           g, W_w, W_b, go1, t1, t2, gW2S, adjW);
        hipLaunchKernelGGL(kP2, dim3(512), dim3(256), 0, stream, adjW, go1, W_w, W_b,
                           t1, t2, gW2S, Wx_b, amask, out1_raw);
        hipLaunchKernelGGL(kP3, dim3(32), dim3(64), 0, stream, out1_raw, amask,
                           clf_w, clf_b, out);
    }
}